// Round 1
// baseline (278.875 us; speedup 1.0000x reference)
//
#include <hip/hip_runtime.h>
#include <hip/hip_bf16.h>

typedef __bf16 bf16x8 __attribute__((ext_vector_type(8)));
typedef float f32x4 __attribute__((ext_vector_type(4)));

#define MFMA(a, b, c) __builtin_amdgcn_mfma_f32_16x16x32_bf16((a), (b), (c), 0, 0, 0)

static __device__ __forceinline__ bf16x8 ld8(const __bf16* p) {
  return *reinterpret_cast<const bf16x8*>(p);
}

// Stage 16 elements (one thread's share of a 128x32 tile row-chunk) into LDS,
// converting fp32 -> bf16 on the fly when the source is fp32.
template<bool SRC_F32>
static __device__ __forceinline__ void stage16(__bf16* __restrict__ dst,
                                               const void* __restrict__ srcv) {
  if constexpr (SRC_F32) {
    const float* src = (const float*)srcv;
#pragma unroll
    for (int j = 0; j < 2; ++j) {
      f32x4 a = *reinterpret_cast<const f32x4*>(src + j * 8);
      f32x4 b = *reinterpret_cast<const f32x4*>(src + j * 8 + 4);
      bf16x8 o;
#pragma unroll
      for (int i = 0; i < 4; ++i) {
        o[i] = (__bf16)a[i];
        o[i + 4] = (__bf16)b[i];
      }
      *reinterpret_cast<bf16x8*>(dst + j * 8) = o;
    }
  } else {
    const __bf16* src = (const __bf16*)srcv;
#pragma unroll
    for (int j = 0; j < 2; ++j)
      *reinterpret_cast<bf16x8*>(dst + j * 8) = *reinterpret_cast<const bf16x8*>(src + j * 8);
  }
}

// C[m][n] = sum_k A[m][k] * W[n][k]   (i.e. A @ W^T), W is fp32 (N x K) row-major.
// A is fp32 or bf16 (M x K) row-major. Output fp32 or bf16 (M x N).
// Tile 128x128, BK=32, 256 threads = 4 waves in 2x2, each wave 64x64 (4x4 MFMA frags).
template<bool A_F32, bool OUT_BF16>
__global__ __launch_bounds__(256)
void gemm_bt(const void* __restrict__ Av, const float* __restrict__ W,
             void* __restrict__ Cv, int M, int N, int K) {
  __shared__ __bf16 lA[128 * 40];  // stride 40 bf16 = 80B (16B-aligned rows, 2-way bank alias only)
  __shared__ __bf16 lB[128 * 40];

  const int tid = threadIdx.x;
  const int ntiles = N >> 7;
  const int mt = blockIdx.x / ntiles;
  const int nt = blockIdx.x % ntiles;
  const int m0 = mt << 7, n0 = nt << 7;
  const int lane = tid & 63, w = tid >> 6;
  const int wm = (w >> 1) << 6;  // wave row offset in tile
  const int wn = (w & 1) << 6;   // wave col offset in tile
  const int fr = lane & 15, fg = lane >> 4;
  const int srow = tid >> 1, scol = (tid & 1) << 4;

  f32x4 acc[4][4] = {};

  for (int k0 = 0; k0 < K; k0 += 32) {
    __syncthreads();  // previous iteration's LDS reads done
    if constexpr (A_F32)
      stage16<true>(lA + srow * 40 + scol,
                    (const float*)Av + (size_t)(m0 + srow) * K + k0 + scol);
    else
      stage16<false>(lA + srow * 40 + scol,
                     (const __bf16*)Av + (size_t)(m0 + srow) * K + k0 + scol);
    stage16<true>(lB + srow * 40 + scol, W + (size_t)(n0 + srow) * K + k0 + scol);
    __syncthreads();  // tile staged

    bf16x8 af[4], bfr[4];
#pragma unroll
    for (int m = 0; m < 4; ++m)
      af[m] = ld8(lA + (wm + m * 16 + fr) * 40 + fg * 8);
#pragma unroll
    for (int n = 0; n < 4; ++n)
      bfr[n] = ld8(lB + (wn + n * 16 + fr) * 40 + fg * 8);
#pragma unroll
    for (int m = 0; m < 4; ++m)
#pragma unroll
      for (int n = 0; n < 4; ++n)
        acc[m][n] = MFMA(af[m], bfr[n], acc[m][n]);
  }

  // C/D layout (verified m89/m91): col = lane&15, row = (lane>>4)*4 + reg
#pragma unroll
  for (int m = 0; m < 4; ++m) {
#pragma unroll
    for (int n = 0; n < 4; ++n) {
#pragma unroll
      for (int r = 0; r < 4; ++r) {
        int row = m0 + wm + m * 16 + fg * 4 + r;
        int col = n0 + wn + n * 16 + fr;
        if constexpr (OUT_BF16)
          ((__bf16*)Cv)[(size_t)row * N + col] = (__bf16)acc[m][n][r];
        else
          ((float*)Cv)[(size_t)row * N + col] = acc[m][n][r];
      }
    }
  }
}

// Causal flash attention over bf16 QKV buffer laid out (B*T, 3*1024) where
// the 3072 axis is [s(3)][h(16)][dk(64)].  Output (B*T, 1024) bf16, col = h*64+dk.
// Grid: (T/64 q-tiles, B*H). Block: 256 = 4 waves; wave w handles q rows [q0+16w, +16).
__global__ __launch_bounds__(256)
void attn_causal(const __bf16* __restrict__ qkv, __bf16* __restrict__ out) {
  constexpr int T = 2048;
  constexpr float SCALE = 0.125f;  // 1/sqrt(64)
  constexpr float NEG = -1e30f;

  __shared__ __bf16 lVT[64 * 72];     // V^T: [dk][key], stride 72 (144B rows, 16B aligned)
  __shared__ __bf16 lP[4][16 * 72];   // per-wave P: [qrow][key], stride 72

  const int tid = threadIdx.x;
  const int lane = tid & 63, w = tid >> 6;
  const int fr = lane & 15, fg = lane >> 4;
  const int qt = blockIdx.x;
  const int bh = blockIdx.y;
  const int b = bh >> 4, h = bh & 15;
  const int q0 = qt << 6;
  const size_t base = (size_t)b * T * 3072;
  const int hoff = h * 64;

  // Q fragments for this wave's 16 rows (row = fr), dk chunks c=0,1
  const int qrow = q0 + w * 16 + fr;
  bf16x8 qf[2];
#pragma unroll
  for (int c = 0; c < 2; ++c)
    qf[c] = ld8(qkv + base + (size_t)qrow * 3072 + hoff + c * 32 + fg * 8);

  f32x4 o[4] = {};                      // O accum: 4 dk-tiles of 16
  float mrow[4] = {NEG, NEG, NEG, NEG}; // running max, per reg (row fg*4+r)
  float lrow[4] = {0.f, 0.f, 0.f, 0.f}; // running sum

  // V^T staging mapping: thread -> (key, 16-wide dk chunk)
  const int vkey = tid >> 2, vdk = (tid & 3) << 4;

  for (int kt = 0; kt <= qt; ++kt) {
    const int k0 = kt << 6;
    __syncthreads();  // previous PV done reading lVT

    // stage V^T (all 256 threads)
    {
      const __bf16* vsrc = qkv + base + (size_t)(k0 + vkey) * 3072 + 2048 + hoff + vdk;
      bf16x8 v0 = ld8(vsrc), v1 = ld8(vsrc + 8);
#pragma unroll
      for (int i = 0; i < 8; ++i) {
        lVT[(vdk + i) * 72 + vkey] = v0[i];
        lVT[(vdk + 8 + i) * 72 + vkey] = v1[i];
      }
    }

    // S = Q K^T for 4 key sub-tiles of 16
    f32x4 s[4] = {};
#pragma unroll
    for (int n = 0; n < 4; ++n) {
      const int key = k0 + n * 16 + fr;
#pragma unroll
      for (int c = 0; c < 2; ++c) {
        bf16x8 kf = ld8(qkv + base + (size_t)key * 3072 + 1024 + hoff + c * 32 + fg * 8);
        s[n] = MFMA(qf[c], kf, s[n]);
      }
    }

    // scale + causal mask; C layout: col(key)=fr? no: col = lane&15 of C = key sub-index
    float sv[4][4];
    const bool diag = (kt == qt);
#pragma unroll
    for (int n = 0; n < 4; ++n) {
#pragma unroll
      for (int r = 0; r < 4; ++r) {
        float x = s[n][r] * SCALE;
        if (diag) {
          int key = k0 + n * 16 + fr;          // C col = lane&15
          int qr = q0 + w * 16 + fg * 4 + r;   // C row = (lane>>4)*4 + reg
          if (key > qr) x = NEG;
        }
        sv[n][r] = x;
      }
    }

    // row max (across 4 n-tiles in-reg, then 16 lanes of the group)
    float rm[4];
#pragma unroll
    for (int r = 0; r < 4; ++r)
      rm[r] = fmaxf(fmaxf(sv[0][r], sv[1][r]), fmaxf(sv[2][r], sv[3][r]));
#pragma unroll
    for (int r = 0; r < 4; ++r) {
#pragma unroll
      for (int mask = 1; mask < 16; mask <<= 1)
        rm[r] = fmaxf(rm[r], __shfl_xor(rm[r], mask));
    }

    float alpha[4];
#pragma unroll
    for (int r = 0; r < 4; ++r) {
      float mnew = fmaxf(mrow[r], rm[r]);
      alpha[r] = __expf(mrow[r] - mnew);
      mrow[r] = mnew;
    }

    // P = exp(S - m), store to per-wave LDS (bf16), row sum
    float rs[4] = {0.f, 0.f, 0.f, 0.f};
#pragma unroll
    for (int n = 0; n < 4; ++n) {
#pragma unroll
      for (int r = 0; r < 4; ++r) {
        float p = __expf(sv[n][r] - mrow[r]);
        rs[r] += p;
        lP[w][(fg * 4 + r) * 72 + n * 16 + fr] = (__bf16)p;
      }
    }
#pragma unroll
    for (int r = 0; r < 4; ++r) {
#pragma unroll
      for (int mask = 1; mask < 16; mask <<= 1)
        rs[r] += __shfl_xor(rs[r], mask);
      lrow[r] = lrow[r] * alpha[r] + rs[r];
    }

    // rescale O
#pragma unroll
    for (int n = 0; n < 4; ++n)
#pragma unroll
      for (int r = 0; r < 4; ++r)
        o[n][r] *= alpha[r];

    __syncthreads();  // lVT staged (and lP written - same wave anyway)

    // O += P V : A = P (16 x 64 keys), B = V^T frags (col = dk, k = key)
#pragma unroll
    for (int c = 0; c < 2; ++c) {
      bf16x8 pf = ld8(lP[w] + fr * 72 + c * 32 + fg * 8);
#pragma unroll
      for (int n = 0; n < 4; ++n) {
        bf16x8 vf = ld8(lVT + (n * 16 + fr) * 72 + c * 32 + fg * 8);
        o[n] = MFMA(pf, vf, o[n]);
      }
    }
  }

  // normalize and write out: row = q0 + w*16 + fg*4 + r, col = h*64 + n*16 + fr
#pragma unroll
  for (int n = 0; n < 4; ++n) {
#pragma unroll
    for (int r = 0; r < 4; ++r) {
      int t = q0 + w * 16 + fg * 4 + r;
      float val = o[n][r] / lrow[r];
      out[(size_t)(b * T + t) * 1024 + hoff + n * 16 + fr] = (__bf16)val;
    }
  }
}

extern "C" void kernel_launch(void* const* d_in, const int* in_sizes, int n_in,
                              void* d_out, int out_size, void* d_ws, size_t ws_size,
                              hipStream_t stream) {
  const float* x = (const float*)d_in[0];       // (2,2048,1024) fp32
  const float* w_qkv = (const float*)d_in[1];   // (3072,1024) fp32
  const float* w_o = (const float*)d_in[2];     // (1024,1024) fp32
  float* out = (float*)d_out;                   // (2,2048,1024) fp32

  const int M = 4096;  // B*T
  __bf16* qkv = (__bf16*)d_ws;                                   // 4096 x 3072 bf16
  __bf16* attn = (__bf16*)((char*)d_ws + (size_t)M * 3072 * 2);  // 4096 x 1024 bf16

  // GEMM1: qkv = x @ W_qkv^T  (bf16 out)
  gemm_bt<true, true><<<(M / 128) * (3072 / 128), 256, 0, stream>>>(
      (const void*)x, w_qkv, (void*)qkv, M, 3072, 1024);

  // causal attention
  attn_causal<<<dim3(2048 / 64, 32), 256, 0, stream>>>(qkv, attn);

  // GEMM2: out = attn @ W_o^T  (fp32 out)
  gemm_bt<false, false><<<(M / 128) * (1024 / 128), 256, 0, stream>>>(
      (const void*)attn, w_o, (void*)out, M, 1024, 1024);
}

// Round 2
// 245.078 us; speedup vs baseline: 1.1379x; 1.1379x over previous
//
#include <hip/hip_runtime.h>
#include <hip/hip_bf16.h>

typedef __bf16 bf16x8 __attribute__((ext_vector_type(8)));
typedef float f32x4 __attribute__((ext_vector_type(4)));

#define MFMA(a, b, c) __builtin_amdgcn_mfma_f32_16x16x32_bf16((a), (b), (c), 0, 0, 0)

static __device__ __forceinline__ bf16x8 ld8(const __bf16* p) {
  return *reinterpret_cast<const bf16x8*>(p);
}

// Stage 16 elements into LDS, converting fp32 -> bf16 on the fly when needed.
template<bool SRC_F32>
static __device__ __forceinline__ void stage16(__bf16* __restrict__ dst,
                                               const void* __restrict__ srcv) {
  if constexpr (SRC_F32) {
    const float* src = (const float*)srcv;
#pragma unroll
    for (int j = 0; j < 2; ++j) {
      f32x4 a = *reinterpret_cast<const f32x4*>(src + j * 8);
      f32x4 b = *reinterpret_cast<const f32x4*>(src + j * 8 + 4);
      bf16x8 o;
#pragma unroll
      for (int i = 0; i < 4; ++i) {
        o[i] = (__bf16)a[i];
        o[i + 4] = (__bf16)b[i];
      }
      *reinterpret_cast<bf16x8*>(dst + j * 8) = o;
    }
  } else {
    const __bf16* src = (const __bf16*)srcv;
#pragma unroll
    for (int j = 0; j < 2; ++j)
      *reinterpret_cast<bf16x8*>(dst + j * 8) = *reinterpret_cast<const bf16x8*>(src + j * 8);
  }
}

// C[m][n] = sum_k A[m][k] * W[n][k]  (A @ W^T), W fp32 (N x K) row-major.
// Tile 128x128, BK=32, 4 waves 2x2, each wave 64x64 (4x4 MFMA frags).
// SPLIT mode (GEMM1): cols [0,2048) -> QK buffer (row stride 2048, bf16);
//                     cols [2048,3072) -> VT buffer [b*1024 + (col-2048)][t] bf16.
template<bool A_F32, bool OUT_BF16, bool SPLIT>
__global__ __launch_bounds__(256)
void gemm_bt(const void* __restrict__ Av, const float* __restrict__ W,
             void* __restrict__ Cv, __bf16* __restrict__ VT,
             int M, int N, int K) {
  __shared__ __bf16 lA[128 * 40];
  __shared__ __bf16 lB[128 * 40];

  const int tid = threadIdx.x;
  const int ntiles = N >> 7;
  const int mt = blockIdx.x / ntiles;
  const int nt = blockIdx.x % ntiles;
  const int m0 = mt << 7, n0 = nt << 7;
  const int lane = tid & 63, w = tid >> 6;
  const int wm = (w >> 1) << 6;
  const int wn = (w & 1) << 6;
  const int fr = lane & 15, fg = lane >> 4;
  const int srow = tid >> 1, scol = (tid & 1) << 4;

  f32x4 acc[4][4] = {};

  for (int k0 = 0; k0 < K; k0 += 32) {
    __syncthreads();
    if constexpr (A_F32)
      stage16<true>(lA + srow * 40 + scol,
                    (const float*)Av + (size_t)(m0 + srow) * K + k0 + scol);
    else
      stage16<false>(lA + srow * 40 + scol,
                     (const __bf16*)Av + (size_t)(m0 + srow) * K + k0 + scol);
    stage16<true>(lB + srow * 40 + scol, W + (size_t)(n0 + srow) * K + k0 + scol);
    __syncthreads();

    bf16x8 af[4], bfr[4];
#pragma unroll
    for (int m = 0; m < 4; ++m)
      af[m] = ld8(lA + (wm + m * 16 + fr) * 40 + fg * 8);
#pragma unroll
    for (int n = 0; n < 4; ++n)
      bfr[n] = ld8(lB + (wn + n * 16 + fr) * 40 + fg * 8);
#pragma unroll
    for (int m = 0; m < 4; ++m)
#pragma unroll
      for (int n = 0; n < 4; ++n)
        acc[m][n] = MFMA(af[m], bfr[n], acc[m][n]);
  }

  // C/D layout: col = lane&15, row = (lane>>4)*4 + reg
#pragma unroll
  for (int m = 0; m < 4; ++m) {
#pragma unroll
    for (int n = 0; n < 4; ++n) {
#pragma unroll
      for (int r = 0; r < 4; ++r) {
        int row = m0 + wm + m * 16 + fg * 4 + r;
        int col = n0 + wn + n * 16 + fr;
        if constexpr (SPLIT) {
          int b = row >> 11, t = row & 2047;
          if (col >= 2048) {
            // V transposed: VT[(b*1024 + hdk)][t]
            VT[((size_t)(b << 10) + (col - 2048)) * 2048 + t] = (__bf16)acc[m][n][r];
          } else {
            ((__bf16*)Cv)[(size_t)row * 2048 + col] = (__bf16)acc[m][n][r];
          }
        } else if constexpr (OUT_BF16) {
          ((__bf16*)Cv)[(size_t)row * N + col] = (__bf16)acc[m][n][r];
        } else {
          ((float*)Cv)[(size_t)row * N + col] = acc[m][n][r];
        }
      }
    }
  }
}

// Barrier-free causal flash attention.
// qk: (B*T, 2048) bf16, col = s(0=Q,1=K)*1024 + h*64 + dk.
// vt: (B*1024, 2048) bf16 = V^T per (b,h): row b*1024 + h*64 + dk, col = t.
// out: (B*T, 1024) bf16.
// Grid: 1024 blocks x 256. Each wave = one independent 16-row q-tile.
// Task g = blockIdx.x*4 + w; qt = 127 - (g>>5) (LPT: longest first); bh = g&31.
__global__ __launch_bounds__(256)
void attn_causal2(const __bf16* __restrict__ qk, const __bf16* __restrict__ vt,
                  __bf16* __restrict__ out) {
  constexpr float SCALE = 0.125f;  // 1/sqrt(64)
  constexpr float NEG = -1e30f;

  __shared__ __bf16 lP[4][16 * 72];  // per-wave P: [qrow][key], stride 72

  const int tid = threadIdx.x;
  const int lane = tid & 63, w = tid >> 6;
  const int fr = lane & 15, fg = lane >> 4;
  const int g = blockIdx.x * 4 + w;
  const int qt = 127 - (g >> 5);
  const int bh = g & 31;
  const int b = bh >> 4, h = bh & 15;
  const int q0 = qt << 4;
  const int hoff = h * 64;
  const size_t qkbase = (size_t)b * 2048 * 2048;
  const size_t vbase = (size_t)(b << 10 | hoff) * 2048;

  // Q fragments: row = fr (16 rows), dk chunks c
  bf16x8 qf[2];
#pragma unroll
  for (int c = 0; c < 2; ++c)
    qf[c] = ld8(qk + qkbase + (size_t)(q0 + fr) * 2048 + hoff + c * 32 + fg * 8);

  f32x4 o[4] = {};
  float mrow[4] = {NEG, NEG, NEG, NEG};
  float lrow[4] = {0.f, 0.f, 0.f, 0.f};

  const int nkt = (q0 + 16 + 63) >> 6;  // 64-key tiles covering keys [0, q0+16)
  for (int kt = 0; kt < nkt; ++kt) {
    const int k0 = kt << 6;

    // S = Q K^T (4 key sub-tiles of 16)
    f32x4 s[4] = {};
#pragma unroll
    for (int n = 0; n < 4; ++n) {
      const __bf16* kp = qk + qkbase + (size_t)(k0 + n * 16 + fr) * 2048 + 1024 + hoff;
#pragma unroll
      for (int c = 0; c < 2; ++c)
        s[n] = MFMA(qf[c], ld8(kp + c * 32 + fg * 8), s[n]);
    }

    // scale + causal mask (only final tile can violate causality)
    float sv[4][4];
    const bool diag = (kt == nkt - 1);
#pragma unroll
    for (int n = 0; n < 4; ++n) {
#pragma unroll
      for (int r = 0; r < 4; ++r) {
        float x = s[n][r] * SCALE;
        if (diag) {
          int key = k0 + n * 16 + fr;       // C col
          int qr = q0 + fg * 4 + r;         // C row
          if (key > qr) x = NEG;
        }
        sv[n][r] = x;
      }
    }

    // row max: in-reg over 4 n-tiles, then across the 16-lane group
    float rm[4];
#pragma unroll
    for (int r = 0; r < 4; ++r)
      rm[r] = fmaxf(fmaxf(sv[0][r], sv[1][r]), fmaxf(sv[2][r], sv[3][r]));
#pragma unroll
    for (int r = 0; r < 4; ++r)
#pragma unroll
      for (int mask = 1; mask < 16; mask <<= 1)
        rm[r] = fmaxf(rm[r], __shfl_xor(rm[r], mask));

    float alpha[4];
#pragma unroll
    for (int r = 0; r < 4; ++r) {
      float mnew = fmaxf(mrow[r], rm[r]);
      alpha[r] = __expf(mrow[r] - mnew);
      mrow[r] = mnew;
    }

    // P = exp(S - m) -> per-wave LDS (bf16); row sums
    float rs[4] = {0.f, 0.f, 0.f, 0.f};
#pragma unroll
    for (int n = 0; n < 4; ++n) {
#pragma unroll
      for (int r = 0; r < 4; ++r) {
        float p = __expf(sv[n][r] - mrow[r]);
        rs[r] += p;
        lP[w][(fg * 4 + r) * 72 + n * 16 + fr] = (__bf16)p;
      }
    }
#pragma unroll
    for (int r = 0; r < 4; ++r) {
#pragma unroll
      for (int mask = 1; mask < 16; mask <<= 1)
        rs[r] += __shfl_xor(rs[r], mask);
      lrow[r] = lrow[r] * alpha[r] + rs[r];
    }

    // rescale O
#pragma unroll
    for (int n = 0; n < 4; ++n)
#pragma unroll
      for (int r = 0; r < 4; ++r)
        o[n][r] *= alpha[r];

    // O += P V ; B-frag from VT: 8 contiguous keys per lane (16B load)
#pragma unroll
    for (int c = 0; c < 2; ++c) {
      bf16x8 pf = ld8(lP[w] + fr * 72 + c * 32 + fg * 8);
#pragma unroll
      for (int n = 0; n < 4; ++n) {
        bf16x8 vf = ld8(vt + vbase + (size_t)(n * 16 + fr) * 2048 + k0 + c * 32 + fg * 8);
        o[n] = MFMA(pf, vf, o[n]);
      }
    }
  }

  // write out: row = q0 + fg*4 + r, col = h*64 + n*16 + fr
#pragma unroll
  for (int n = 0; n < 4; ++n) {
#pragma unroll
    for (int r = 0; r < 4; ++r) {
      int t = q0 + fg * 4 + r;
      float val = o[n][r] / lrow[r];
      out[((size_t)(b * 2048 + t)) * 1024 + hoff + n * 16 + fr] = (__bf16)val;
    }
  }
}

extern "C" void kernel_launch(void* const* d_in, const int* in_sizes, int n_in,
                              void* d_out, int out_size, void* d_ws, size_t ws_size,
                              hipStream_t stream) {
  const float* x = (const float*)d_in[0];       // (2,2048,1024) fp32
  const float* w_qkv = (const float*)d_in[1];   // (3072,1024) fp32
  const float* w_o = (const float*)d_in[2];     // (1024,1024) fp32
  float* out = (float*)d_out;                   // (2,2048,1024) fp32

  const int M = 4096;  // B*T
  __bf16* qk = (__bf16*)d_ws;                                        // 4096 x 2048 bf16
  __bf16* vt = (__bf16*)((char*)d_ws + (size_t)M * 2048 * 2);        // 2048 x 2048 bf16 (V^T)
  __bf16* attn = (__bf16*)((char*)d_ws + (size_t)M * 3072 * 2);      // 4096 x 1024 bf16

  // GEMM1: qkv = x @ W_qkv^T ; Q,K -> qk buffer, V -> vt transposed
  gemm_bt<true, true, true><<<(M / 128) * (3072 / 128), 256, 0, stream>>>(
      (const void*)x, w_qkv, (void*)qk, vt, M, 3072, 1024);

  // causal attention (barrier-free, LPT order)
  attn_causal2<<<1024, 256, 0, stream>>>(qk, vt, attn);

  // GEMM2: out = attn @ W_o^T (fp32 out)
  gemm_bt<false, false, false><<<(M / 128) * (1024 / 128), 256, 0, stream>>>(
      (const void*)attn, w_o, (void*)out, nullptr, M, 1024, 1024);
}